// Round 4
// baseline (624.095 us; speedup 1.0000x reference)
//
#include <hip/hip_runtime.h>
#include <hip/hip_fp16.h>
#include <math.h>

#define H 512
#define W 512
#define S (H*W)
#define BS 16
#define CH 3
#define NP (BS*CH)

#define T     10          // Chebyshev steps, all fused
#define NW    16          // waves per block
#define RPW   4           // rows per wave (in registers)
#define R     (NW*RPW)    // 64 extended rows per block
#define STRIP (R - 2*T)   // 44 rows correct after T steps
#define NBX   12          // 12*44 = 528 >= 512
#define NTHR  (NW*64)     // 1024

typedef unsigned int   uint_t;
typedef unsigned short ush;

struct F8 { float f[8]; };

__device__ __forceinline__ F8 unpk(uint4 r) {
  F8 o;
  float2 a = __half22float2(*(__half2*)&r.x); o.f[0]=a.x; o.f[1]=a.y;
  float2 b = __half22float2(*(__half2*)&r.y); o.f[2]=b.x; o.f[3]=b.y;
  float2 c = __half22float2(*(__half2*)&r.z); o.f[4]=c.x; o.f[5]=c.y;
  float2 d = __half22float2(*(__half2*)&r.w); o.f[6]=d.x; o.f[7]=d.y;
  return o;
}
__device__ __forceinline__ uint_t pk2(float a, float b) {
  __half2 h = __floats2half2_rn(a, b); return *(uint_t*)&h;
}
__device__ __forceinline__ uint4 pk8(const float* f) {
  return make_uint4(pk2(f[0],f[1]), pk2(f[2],f[3]), pk2(f[4],f[5]), pk2(f[6],f[7]));
}
__device__ __forceinline__ uint4 pkf8(float4 a, float4 b) {
  return make_uint4(pk2(a.x,a.y), pk2(a.z,a.w), pk2(b.x,b.y), pk2(b.z,b.w));
}
__device__ __forceinline__ float hi_h(uint_t u){ return __half22float2(*(__half2*)&u).y; }
__device__ __forceinline__ float lo_h(uint_t u){ return __half22float2(*(__half2*)&u).x; }

// tau = 1/(5 + 4 cos(pi(2k-1)/20)), Lebedev order k = 1,10,2,9,3,8,4,7,5,6
__device__ const float TAUS[T] = {
  0.11172248f, 0.95306479f, 0.11676753f, 0.69639146f, 0.12773959f,
  0.46049561f, 0.14671469f, 0.31406661f, 0.17775436f, 0.22860982f };

// All 10 Chebyshev steps fused. x lives packed-fp16 in REGISTERS (4 rows per
// wave); LDS holds only a parity double-buffered boundary-row exchange
// (2 rows/wave/step, 64 KiB). b/wc/wr packed-fp16 in regs for the whole
// kernel. amdgpu_waves_per_eu(4,4) pins the allocator to the 128-VGPR /
// 4-waves-per-SIMD point that the 1-block/CU LDS footprint implies (round 2
// let the heuristic pick 64 VGPRs -> 1.2 GB of scratch spill traffic).
__global__ void __launch_bounds__(NTHR)
__attribute__((amdgpu_waves_per_eu(4, 4)))
cheb_fused(const float* __restrict__ Bsrc, const float* __restrict__ WCs,
           const float* __restrict__ WRs, float* __restrict__ OUT)
{
  __shared__ __align__(16) ush ex[2][NW][2][W];   // 64 KiB exchange

  const int j  = blockIdx.y;                    // plane 0..47
  const int bb = j / CH;                        // batch
  const int y0 = (int)blockIdx.x * STRIP;       // first interior row
  const int ys = y0 - T;                        // first extended row
  const int tid = (int)threadIdx.x;
  const int wv = tid >> 6, lane = tid & 63;
  const uint4 zz = make_uint4(0,0,0,0);

  const float* bp = Bsrc + (size_t)j  * S;
  const float* wc = WCs  + (size_t)bb * (size_t)(H-1) * W;
  const float* wr = WRs  + (size_t)bb * (size_t)H * (W-1);

  // ---- init: load fp32 inputs once, pack to fp16 regs; x0 = fp16(b) ----
  const int rb = wv * RPW;                      // wave's first row (tile-rel)
  uint4 xpk[RPW], bpk[RPW], wca[RPW+1], wrp[RPW];
  float wlmr[RPW];
#pragma unroll
  for (int i = 0; i < RPW; ++i) {
    const int y = ys + rb + i;
    uint4 bv = zz, wrv = zz;
    if ((unsigned)y < H) {
      const float* p = bp + (size_t)y*W + lane*8;
      bv = pkf8(*(const float4*)p, *(const float4*)(p + 4));
      // wr rows have stride 511 floats (unaligned) -> scalar loads; col 511=0
      const float* q = wr + (size_t)y*(W-1) + lane*8;
      const float a0=q[0],a1=q[1],a2=q[2],a3=q[3],a4=q[4],a5=q[5],a6=q[6];
      const float a7 = (lane < 63) ? q[7] : 0.f;
      wrv = make_uint4(pk2(a0,a1), pk2(a2,a3), pk2(a4,a5), pk2(a6,a7));
    }
    bpk[i] = bv; xpk[i] = bv; wrp[i] = wrv;
    // left-neighbor row-weight for px 0 of this lane: step-invariant, hoisted
    const uint_t uw = (uint_t)__shfl_up((int)wrv.w, 1);
    wlmr[i] = lane ? hi_h(uw) : 0.f;
  }
#pragma unroll
  for (int i = 0; i <= RPW; ++i) {              // wc rows y(0)-1 .. y(RPW-1)
    const int y = ys + rb - 1 + i;
    uint4 wv4 = zz;
    if ((unsigned)y < (H-1)) {
      const float* p = wc + (size_t)y*W + lane*8;
      wv4 = pkf8(*(const float4*)p, *(const float4*)(p + 4));
    }
    wca[i] = wv4;
  }

  // ---- 10 steps; one barrier per step (parity-buffered exchange) ----
#pragma unroll 1
  for (int t = 0; t < T; ++t) {
    const float tau = TAUS[t];
    const int buf = t & 1;
    *(uint4*)&ex[buf][wv][0][lane*8] = xpk[0];
    *(uint4*)&ex[buf][wv][1][lane*8] = xpk[RPW-1];
    __syncthreads();
    const uint4 xup = wv          ? *(const uint4*)&ex[buf][wv-1][1][lane*8] : zz;
    const uint4 xdn = (wv < NW-1) ? *(const uint4*)&ex[buf][wv+1][0][lane*8] : zz;
    const bool last = (t == T-1);

    uint4 xprev = xup;                          // old x of row i-1
#pragma unroll
    for (int i = 0; i < RPW; ++i) {
      const uint4 xc_pk = xpk[i];
      const uint4 xd_pk = (i < RPW-1) ? xpk[i+1] : xdn;
      const uint_t ux  = (uint_t)__shfl_up((int)xc_pk.w, 1);
      const float xl0  = lane ? hi_h(ux) : 0.f;
      const uint_t dxp = (uint_t)__shfl_down((int)xc_pk.x, 1);
      const float xr7  = (lane < 63) ? lo_h(dxp) : 0.f;
      const F8 xc = unpk(xc_pk), xu = unpk(xprev), xd = unpk(xd_pk);
      const F8 wu = unpk(wca[i]), wd = unpk(wca[i+1]);
      const F8 w  = unpk(wrp[i]), b  = unpk(bpk[i]);
      float o[8];
#pragma unroll
      for (int p = 0; p < 8; ++p) {
        const float wl  = p ? w.f[p-1] : wlmr[i];
        const float wrv = w.f[p];
        const float xl  = p ? xc.f[p-1] : xl0;
        const float xr  = (p < 7) ? xc.f[p+1] : xr7;
        const float kv  = 1.f + wu.f[p] + wd.f[p] + wl + wrv;
        const float av  = kv * xc.f[p] - wu.f[p]*xu.f[p] - wd.f[p]*xd.f[p]
                          - wl*xl - wrv*xr;
        o[p] = xc.f[p] + tau * (b.f[p] - av);
      }
      xprev = xc_pk;                            // old center -> next row's up
      if (!last) {
        xpk[i] = pk8(o);
      } else {
        const int y = ys + rb + i;
        if (y >= y0 && y < y0 + STRIP && y < H) {
          float* dst = OUT + (size_t)j*S + (size_t)y*W + lane*8;
          *(float4*)dst       = make_float4(o[0],o[1],o[2],o[3]);
          *(float4*)(dst + 4) = make_float4(o[4],o[5],o[6],o[7]);
        }
      }
    }
  }
}

extern "C" void kernel_launch(void* const* d_in, const int* in_sizes, int n_in,
                              void* d_out, int out_size, void* d_ws, size_t ws_size,
                              hipStream_t stream) {
  (void)in_sizes; (void)n_in; (void)out_size; (void)d_ws; (void)ws_size;
  const float* Bp = (const float*)d_in[0];
  const float* WC = (const float*)d_in[1];
  const float* WR = (const float*)d_in[2];
  dim3 grid(NBX, NP), block(NTHR);
  cheb_fused<<<grid, block, 0, stream>>>(Bp, WC, WR, (float*)d_out);
}